// Round 1
// baseline (296.731 us; speedup 1.0000x reference)
//
#include <hip/hip_runtime.h>
#include <math.h>

// SUFGConv: B=2, N=2048, F=32. Key observation: xc rows [0:2048) are dead in the
// reference; both big einsums stream the same d_list[:, 2048:, :] slice (100.7 MB).
//
// k_pre  : xw[b][n][o] = x@weight (blocked layout) + d_out = bias broadcast
// k_pass1: x_shrink_blocked = shrink(filt * (d1 @ xw))      (768 blocks)
// k_pass2: d_out += y2 @ x_shrink   (K split 3-way, atomicAdd)  (774 blocks)

#define NB   2
#define NN   2048
#define DP   2049          // d_list row pitch (N+1)
#define M1   6144          // x_shrink rows per batch
#define OUTR 2049
#define KC   64            // K chunk
#define TM   16            // rows per block

#define XW_OFF 0           // ws float offsets: xw_b = [2][512][32][4] = 131072 floats
#define XS_OFF 131072      // xs_b = [2][1536][32][4] = 393216 floats

__device__ __forceinline__ void cp4(const float* g, float* l) {
  __builtin_amdgcn_global_load_lds((const __attribute__((address_space(1))) void*)g,
                                   (__attribute__((address_space(3))) void*)l, 4, 0, 0);
}
__device__ __forceinline__ void cp16(const float* g, float* l) {
  __builtin_amdgcn_global_load_lds((const __attribute__((address_space(1))) void*)g,
                                   (__attribute__((address_space(3))) void*)l, 16, 0, 0);
}

__global__ __launch_bounds__(256) void k_pre(const float* __restrict__ x,
                                             const float* __restrict__ wgt,
                                             const float* __restrict__ bias,
                                             float* __restrict__ xw_b,
                                             float* __restrict__ out) {
  const int bid = blockIdx.x, tid = threadIdx.x;
  if (bid < 512) {
    const int b = bid >> 8, tile = bid & 255;
    const int n = tile * 8 + (tid >> 5), o = tid & 31;
    const float* xr = x + ((size_t)b * NN + n) * 32;
    float acc = 0.f;
#pragma unroll
    for (int f = 0; f < 32; ++f) acc = fmaf(xr[f], wgt[f * 32 + o], acc);
    // blocked: xw_b[b][n/4][o][n%4]
    xw_b[((b * 512 + (n >> 2)) * 32 + o) * 4 + (n & 3)] = acc;
  } else {
    const int idx = (bid - 512) * 256 + tid;
    if (idx < NB * OUTR * 32) out[idx] = bias[idx & 31];
  }
}

__global__ __launch_bounds__(256) void k_pass1(const float* __restrict__ dlist,
                                               const float* __restrict__ xw_b,
                                               const float* __restrict__ filt,
                                               float* __restrict__ xs_b) {
  __shared__ float dl[2][TM][KC];     // 8 KB
  __shared__ float xl[2][16][128];    // 16 KB, blocked [k4][o][4]

  const int bid = blockIdx.x;
  const int b = bid / 384, tile = bid % 384;
  const int row0 = tile * TM;
  const int tid = threadIdx.x, w = tid >> 6, lane = tid & 63;
  const int o = lane & 31, g = lane >> 5;

  const float* dbase = dlist + ((size_t)(b * 8192 + 2048 + row0)) * DP + 1;
  const float* xwb = xw_b + b * 65536;

  auto stage = [&](int buf, int k0) {
    // d rows: wave w stages its 4 rows, width-4 (rows are only 4B-aligned)
#pragma unroll
    for (int i = 0; i < 4; ++i) {
      const int r = w * 4 + i;
      cp4(dbase + (size_t)r * DP + k0 + lane, &dl[buf][r][0]);
    }
    // xw chunk: contiguous 2048 floats in blocked layout, width-16
#pragma unroll
    for (int i = 0; i < 2; ++i) {
      const int inst = w * 2 + i;
      cp16(xwb + k0 * 32 + inst * 256 + lane * 4, &xl[buf][0][0] + inst * 256);
    }
  };

  float acc0 = 0.f, acc1 = 0.f;
  const int r0 = w * 4 + g * 2, r1 = r0 + 1;

  stage(0, 0);
#pragma unroll 1
  for (int c = 0; c < 32; ++c) {
    __syncthreads();                       // drains vmcnt: chunk c resident
    if (c + 1 < 32) stage((c + 1) & 1, (c + 1) * KC);  // prefetch flies under compute
    const int buf = c & 1;
#pragma unroll
    for (int k4 = 0; k4 < 16; ++k4) {
      const float4 xq = *(const float4*)&xl[buf][k4][o * 4];
      const float4 d0 = *(const float4*)&dl[buf][r0][k4 * 4];
      const float4 d1 = *(const float4*)&dl[buf][r1][k4 * 4];
      acc0 = fmaf(d0.x, xq.x, acc0); acc0 = fmaf(d0.y, xq.y, acc0);
      acc0 = fmaf(d0.z, xq.z, acc0); acc0 = fmaf(d0.w, xq.w, acc0);
      acc1 = fmaf(d1.x, xq.x, acc1); acc1 = fmaf(d1.y, xq.y, acc1);
      acc1 = fmaf(d1.z, xq.z, acc1); acc1 = fmaf(d1.w, xq.w, acc1);
    }
  }

  const float THR = 0.08628973f;  // sqrt(2*ln(2048))/sqrt(2048)
  const int   m[2] = {row0 + r0, row0 + r1};
  const float a[2] = {acc0, acc1};
#pragma unroll
  for (int i = 0; i < 2; ++i) {
    float v = a[i] * filt[2048 + m[i]];
    if (m[i] >= 2048) {                    // 'high' rows: soft threshold
      const float t = fabsf(v) - THR;
      v = t > 0.f ? copysignf(t, v) : 0.f;
    }
    xs_b[((size_t)(b * 1536 + (m[i] >> 2)) * 32 + o) * 4 + (m[i] & 3)] = v;
  }
}

__global__ __launch_bounds__(256) void k_pass2(const float* __restrict__ dlist,
                                               const float* __restrict__ xs_b,
                                               float* __restrict__ out) {
  __shared__ float dl[2][TM][KC];
  __shared__ float xl[2][16][128];

  const int tile = blockIdx.x, b = blockIdx.y, seg = blockIdx.z;
  const int row0 = tile * TM;         // output row (k) base
  const int m0 = seg * 2048;          // K segment base
  const int tid = threadIdx.x, w = tid >> 6, lane = tid & 63;
  const int o = lane & 31, g = lane >> 5;

  // y2[b][k][m] = d_list flat at b*8192*2049 + 2048*2049 + k*6144 + m (16B aligned)
  const float* ybase = dlist + (size_t)b * 8192 * DP + (size_t)2048 * DP + m0;
  const float* xsb = xs_b + b * 196608 + m0 * 32;

  auto stage = [&](int buf, int k0) {
    {
      const int rloc = w * 4 + (lane >> 4);
      int rg = row0 + rloc; if (rg > 2048) rg = 2048;   // clamp tail rows
      cp16(ybase + (size_t)rg * 6144 + k0 + (lane & 15) * 4, &dl[buf][w * 4][0]);
    }
#pragma unroll
    for (int i = 0; i < 2; ++i) {
      const int inst = w * 2 + i;
      cp16(xsb + k0 * 32 + inst * 256 + lane * 4, &xl[buf][0][0] + inst * 256);
    }
  };

  float acc0 = 0.f, acc1 = 0.f;
  const int r0 = w * 4 + g * 2, r1 = r0 + 1;

  stage(0, 0);
#pragma unroll 1
  for (int c = 0; c < 32; ++c) {
    __syncthreads();
    if (c + 1 < 32) stage((c + 1) & 1, (c + 1) * KC);
    const int buf = c & 1;
#pragma unroll
    for (int k4 = 0; k4 < 16; ++k4) {
      const float4 xq = *(const float4*)&xl[buf][k4][o * 4];
      const float4 d0 = *(const float4*)&dl[buf][r0][k4 * 4];
      const float4 d1 = *(const float4*)&dl[buf][r1][k4 * 4];
      acc0 = fmaf(d0.x, xq.x, acc0); acc0 = fmaf(d0.y, xq.y, acc0);
      acc0 = fmaf(d0.z, xq.z, acc0); acc0 = fmaf(d0.w, xq.w, acc0);
      acc1 = fmaf(d1.x, xq.x, acc1); acc1 = fmaf(d1.y, xq.y, acc1);
      acc1 = fmaf(d1.z, xq.z, acc1); acc1 = fmaf(d1.w, xq.w, acc1);
    }
  }

  const int   k[2] = {row0 + r0, row0 + r1};
  const float a[2] = {acc0, acc1};
#pragma unroll
  for (int i = 0; i < 2; ++i)
    if (k[i] <= 2048)
      atomicAdd(&out[((size_t)b * OUTR + k[i]) * 32 + o], a[i]);
}

extern "C" void kernel_launch(void* const* d_in, const int* in_sizes, int n_in,
                              void* d_out, int out_size, void* d_ws, size_t ws_size,
                              hipStream_t stream) {
  const float* x     = (const float*)d_in[0];
  const float* dlist = (const float*)d_in[1];
  const float* wgt   = (const float*)d_in[2];
  const float* filt  = (const float*)d_in[3];
  const float* bias  = (const float*)d_in[4];
  float* out = (float*)d_out;
  float* ws  = (float*)d_ws;
  float* xw_b = ws + XW_OFF;
  float* xs_b = ws + XS_OFF;

  k_pre<<<dim3(1025), dim3(256), 0, stream>>>(x, wgt, bias, xw_b, out);
  k_pass1<<<dim3(768), dim3(256), 0, stream>>>(dlist, xw_b, filt, xs_b);
  k_pass2<<<dim3(129, 2, 3), dim3(256), 0, stream>>>(dlist, xs_b, out);
}

// Round 2
// 273.343 us; speedup vs baseline: 1.0856x; 1.0856x over previous
//
#include <hip/hip_runtime.h>
#include <math.h>

// SUFGConv fp32. xc rows [0:2048) are dead; both big einsums stream d_list[:,2048:,:].
//
// k_pre    : xw[b][k][o] = x @ weight                      (128 blocks)
// k_pass1  : p1[s] = d1-seg @ xw  (filt folded in)          (48,2,8) TM=128
// k_shrink : xs = shrink(sum_s p1[s])                       (96 blocks)
// k_pass2  : p2[s] = y2-seg @ xs                            (17,2,16) TM=128
// k_reduce : out = bias + sum_s p2[s]                       (129 blocks)
//
// GEMM blocks: 256 thr, per-thread 4 rows x 4 cols (16 acc). A (d_list rows) is
// LDS-staged via global_load_lds, double-buffered, XOR-swizzled at 16B grain:
// LDS slot k4 of row r holds global chunk k4 ^ ((r>>2)&7)  -- applied on BOTH
// the stage source address and the ds_read address (same involution), making
// the 8-distinct-row ds_read_b128 pattern conflict-free. B (xw/xs) is read
// per-lane from global (L2-resident, 8-way broadcast) -> LDS traffic = 1B/FMA.
// Each wave stages exactly the 32 LDS rows it later reads.

#define DP 2049
#define THRS 0.08628973f   // sqrt(2*ln(2048))/sqrt(2048)

#define XW_OFF 0
#define XS_OFF 131072
#define P1_OFF 524288            // 8 * 393216
#define P2_OFF 3670016           // 16 * 139264

__device__ __forceinline__ void cp4(const float* g, float* l) {
  __builtin_amdgcn_global_load_lds((const __attribute__((address_space(1))) void*)g,
                                   (__attribute__((address_space(3))) void*)l, 4, 0, 0);
}
__device__ __forceinline__ void cp16(const float* g, float* l) {
  __builtin_amdgcn_global_load_lds((const __attribute__((address_space(1))) void*)g,
                                   (__attribute__((address_space(3))) void*)l, 16, 0, 0);
}

__global__ __launch_bounds__(256) void k_pre(const float* __restrict__ x,
                                             const float* __restrict__ wgt,
                                             float* __restrict__ xw) {
  const int gid = blockIdx.x * 256 + threadIdx.x;   // 32768 threads
  const int r = gid >> 3, c0 = (gid & 7) * 4;       // r in [0,4096)
  const float* xr = x + (size_t)r * 32;
  float4 acc = {0.f, 0.f, 0.f, 0.f};
#pragma unroll
  for (int f = 0; f < 32; ++f) {
    const float xv = xr[f];
    const float4 wv = *(const float4*)(wgt + f * 32 + c0);
    acc.x = fmaf(xv, wv.x, acc.x); acc.y = fmaf(xv, wv.y, acc.y);
    acc.z = fmaf(xv, wv.z, acc.z); acc.w = fmaf(xv, wv.w, acc.w);
  }
  *(float4*)(xw + (size_t)r * 32 + c0) = acc;
}

__global__ __launch_bounds__(256) void k_pass1(const float* __restrict__ dlist,
                                               const float* __restrict__ xw,
                                               const float* __restrict__ filt,
                                               float* __restrict__ p1) {
  __shared__ float dl[2][4096];                     // 2 x 16KB
  const int tile = blockIdx.x;                      // 0..47  (128 rows each)
  const int b    = blockIdx.y;                      // 0..1
  const int s    = blockIdx.z;                      // 0..7   (K segment, 256 each)
  const int tid = threadIdx.x, wv = tid >> 6, lane = tid & 63;
  const int r_t = tid >> 3, c_t = tid & 7;
  const int r0 = r_t * 4, c0 = c_t * 4, swzr = r_t & 7;

  const int k_seg = s * 256;
  const float* dbase = dlist + ((size_t)b * 8192 + 2048 + tile * 128) * DP + 1 + k_seg;
  const float* xwb   = xw + ((size_t)b * 2048 + k_seg) * 32;

  // stage: cp4, 16 instrs/wave/chunk; instr ii covers LDS rows wv*32+2ii..+1.
  // swz(row) = (row>>2)&7 = (ii>>1)&7 (uniform per instr).
  const int rhalf = lane >> 5, j = lane & 31, j16 = j >> 2, jrem = j & 3;
  const float* sbase = dbase + (size_t)(wv * 32 + rhalf) * DP + jrem;

  auto stage = [&](int buf, int kc) {
    float* lb = &dl[buf][wv * 1024];
#pragma unroll
    for (int ii = 0; ii < 16; ++ii) {
      const int scol = ((j16 ^ ((ii >> 1) & 7)) << 2);
      cp4(sbase + kc + (size_t)(2 * ii) * DP + scol, lb + ii * 64);
    }
  };

  float4 acc[4];
#pragma unroll
  for (int i = 0; i < 4; ++i) acc[i] = {0.f, 0.f, 0.f, 0.f};

  stage(0, 0);
#pragma unroll 1
  for (int c = 0; c < 8; ++c) {
    __syncthreads();
    if (c < 7) stage((c + 1) & 1, (c + 1) * 32);
    const float* dbuf = &dl[c & 1][0];
    const float* xwc  = xwb + (size_t)c * 32 * 32;
#pragma unroll
    for (int k4 = 0; k4 < 8; ++k4) {
      const float4 w0 = *(const float4*)(xwc + (k4 * 4 + 0) * 32 + c0);
      const float4 w1 = *(const float4*)(xwc + (k4 * 4 + 1) * 32 + c0);
      const float4 w2 = *(const float4*)(xwc + (k4 * 4 + 2) * 32 + c0);
      const float4 w3 = *(const float4*)(xwc + (k4 * 4 + 3) * 32 + c0);
      const int colf = ((k4 ^ swzr) << 2);
#pragma unroll
      for (int i = 0; i < 4; ++i) {
        const float4 d = *(const float4*)(dbuf + (r0 + i) * 32 + colf);
        float4& a = acc[i];
        a.x = fmaf(d.x, w0.x, a.x); a.y = fmaf(d.x, w0.y, a.y); a.z = fmaf(d.x, w0.z, a.z); a.w = fmaf(d.x, w0.w, a.w);
        a.x = fmaf(d.y, w1.x, a.x); a.y = fmaf(d.y, w1.y, a.y); a.z = fmaf(d.y, w1.z, a.z); a.w = fmaf(d.y, w1.w, a.w);
        a.x = fmaf(d.z, w2.x, a.x); a.y = fmaf(d.z, w2.y, a.y); a.z = fmaf(d.z, w2.z, a.z); a.w = fmaf(d.z, w2.w, a.w);
        a.x = fmaf(d.w, w3.x, a.x); a.y = fmaf(d.w, w3.y, a.y); a.z = fmaf(d.w, w3.z, a.z); a.w = fmaf(d.w, w3.w, a.w);
      }
    }
  }

  const size_t pbase = ((size_t)(s * 2 + b) * 6144 + tile * 128) * 32;
#pragma unroll
  for (int i = 0; i < 4; ++i) {
    const int m = tile * 128 + r0 + i;
    const float fl = filt[2048 + m];
    float4 v = acc[i];
    v.x *= fl; v.y *= fl; v.z *= fl; v.w *= fl;
    *(float4*)(p1 + pbase + (size_t)(r0 + i) * 32 + c0) = v;
  }
}

__global__ __launch_bounds__(256) void k_shrink(const float* __restrict__ p1,
                                                float* __restrict__ xs) {
  const int q0 = blockIdx.x * 1024 + threadIdx.x;   // 96 blocks
#pragma unroll
  for (int t = 0; t < 4; ++t) {
    const int f4 = q0 + t * 256;                    // [0, 98304)
    const int row = f4 >> 3;                        // [0, 12288)
    const int bb = row / 6144;
    const int m  = row - bb * 6144;
    float4 sum = {0.f, 0.f, 0.f, 0.f};
#pragma unroll
    for (int s = 0; s < 8; ++s) {
      const float4 v = *(const float4*)(p1 + ((size_t)((s * 2 + bb) * 6144 + m) * 8 + (f4 & 7)) * 4);
      sum.x += v.x; sum.y += v.y; sum.z += v.z; sum.w += v.w;
    }
    if (m >= 2048) {
      float t0;
      t0 = fabsf(sum.x) - THRS; sum.x = t0 > 0.f ? copysignf(t0, sum.x) : 0.f;
      t0 = fabsf(sum.y) - THRS; sum.y = t0 > 0.f ? copysignf(t0, sum.y) : 0.f;
      t0 = fabsf(sum.z) - THRS; sum.z = t0 > 0.f ? copysignf(t0, sum.z) : 0.f;
      t0 = fabsf(sum.w) - THRS; sum.w = t0 > 0.f ? copysignf(t0, sum.w) : 0.f;
    }
    *(float4*)(xs + (size_t)f4 * 4) = sum;
  }
}

__global__ __launch_bounds__(256) void k_pass2(const float* __restrict__ dlist,
                                               const float* __restrict__ xs,
                                               float* __restrict__ p2) {
  __shared__ float dl[2][4096];
  const int tile = blockIdx.x;                      // 0..16 (rows k, 128 each)
  const int b    = blockIdx.y;
  const int s    = blockIdx.z;                      // 0..15 (K segment, 384 each)
  const int tid = threadIdx.x, wv = tid >> 6, lane = tid & 63;
  const int r_t = tid >> 3, c_t = tid & 7;
  const int r0 = r_t * 4, c0 = c_t * 4, swzr = r_t & 7;

  const int m0 = s * 384;
  // y2[b][k][m] = d_list flat at b*8192*DP + 2048*DP + k*6144 + m (16B-aligned)
  const float* Abase = dlist + (size_t)b * 8192 * DP + (size_t)2048 * DP + m0;
  const float* xsb   = xs + ((size_t)b * 6144 + m0) * 32;

  const int rloc = lane >> 3, j16 = lane & 7;
  auto stage = [&](int buf, int kc) {
    float* lb = &dl[buf][wv * 1024];
#pragma unroll
    for (int ii = 0; ii < 4; ++ii) {
      const int row_l = wv * 32 + ii * 8 + rloc;
      const int swz = (row_l >> 2) & 7;
      int rowg = tile * 128 + row_l;
      rowg = rowg > 2048 ? 2048 : rowg;             // clamp tail rows
      cp16(Abase + (size_t)rowg * 6144 + kc + ((j16 ^ swz) << 2), lb + ii * 256);
    }
  };

  float4 acc[4];
#pragma unroll
  for (int i = 0; i < 4; ++i) acc[i] = {0.f, 0.f, 0.f, 0.f};

  stage(0, 0);
#pragma unroll 1
  for (int c = 0; c < 12; ++c) {
    __syncthreads();
    if (c < 11) stage((c + 1) & 1, (c + 1) * 32);
    const float* dbuf = &dl[c & 1][0];
    const float* xsc  = xsb + (size_t)c * 32 * 32;
#pragma unroll
    for (int k4 = 0; k4 < 8; ++k4) {
      const float4 w0 = *(const float4*)(xsc + (k4 * 4 + 0) * 32 + c0);
      const float4 w1 = *(const float4*)(xsc + (k4 * 4 + 1) * 32 + c0);
      const float4 w2 = *(const float4*)(xsc + (k4 * 4 + 2) * 32 + c0);
      const float4 w3 = *(const float4*)(xsc + (k4 * 4 + 3) * 32 + c0);
      const int colf = ((k4 ^ swzr) << 2);
#pragma unroll
      for (int i = 0; i < 4; ++i) {
        const float4 d = *(const float4*)(dbuf + (r0 + i) * 32 + colf);
        float4& a = acc[i];
        a.x = fmaf(d.x, w0.x, a.x); a.y = fmaf(d.x, w0.y, a.y); a.z = fmaf(d.x, w0.z, a.z); a.w = fmaf(d.x, w0.w, a.w);
        a.x = fmaf(d.y, w1.x, a.x); a.y = fmaf(d.y, w1.y, a.y); a.z = fmaf(d.y, w1.z, a.z); a.w = fmaf(d.y, w1.w, a.w);
        a.x = fmaf(d.z, w2.x, a.x); a.y = fmaf(d.z, w2.y, a.y); a.z = fmaf(d.z, w2.z, a.z); a.w = fmaf(d.z, w2.w, a.w);
        a.x = fmaf(d.w, w3.x, a.x); a.y = fmaf(d.w, w3.y, a.y); a.z = fmaf(d.w, w3.z, a.z); a.w = fmaf(d.w, w3.w, a.w);
      }
    }
  }

  const size_t pbase = ((size_t)(s * 2 + b) * 2176 + tile * 128) * 32;
#pragma unroll
  for (int i = 0; i < 4; ++i)
    *(float4*)(p2 + pbase + (size_t)(r0 + i) * 32 + c0) = acc[i];
}

__global__ __launch_bounds__(256) void k_reduce(const float* __restrict__ p2,
                                                const float* __restrict__ bias,
                                                float* __restrict__ out) {
  const int idx = blockIdx.x * 256 + threadIdx.x;   // f4 index
  if (idx >= 32784) return;                         // 2*2049*32/4
  const int row = idx >> 3;                         // [0, 4098)
  const int bb = row / 2049;
  const int k  = row - bb * 2049;
  const int o4 = idx & 7;
  float4 sum = *(const float4*)(bias + o4 * 4);
#pragma unroll
  for (int s = 0; s < 16; ++s) {
    const float4 v = *(const float4*)(p2 + ((size_t)((s * 2 + bb) * 2176 + k) * 8 + o4) * 4);
    sum.x += v.x; sum.y += v.y; sum.z += v.z; sum.w += v.w;
  }
  *(float4*)(out + (size_t)idx * 4) = sum;
}

extern "C" void kernel_launch(void* const* d_in, const int* in_sizes, int n_in,
                              void* d_out, int out_size, void* d_ws, size_t ws_size,
                              hipStream_t stream) {
  const float* x     = (const float*)d_in[0];
  const float* dlist = (const float*)d_in[1];
  const float* wgt   = (const float*)d_in[2];
  const float* filt  = (const float*)d_in[3];
  const float* bias  = (const float*)d_in[4];
  float* out = (float*)d_out;
  float* ws  = (float*)d_ws;
  float* xw = ws + XW_OFF;
  float* xs = ws + XS_OFF;
  float* p1 = ws + P1_OFF;
  float* p2 = ws + P2_OFF;

  k_pre   <<<dim3(128),       dim3(256), 0, stream>>>(x, wgt, xw);
  k_pass1 <<<dim3(48, 2, 8),  dim3(256), 0, stream>>>(dlist, xw, filt, p1);
  k_shrink<<<dim3(96),        dim3(256), 0, stream>>>(p1, xs);
  k_pass2 <<<dim3(17, 2, 16), dim3(256), 0, stream>>>(dlist, xs, p2);
  k_reduce<<<dim3(129),       dim3(256), 0, stream>>>(p2, bias, out);
}